// Round 1
// baseline (229.744 us; speedup 1.0000x reference)
//
#include <hip/hip_runtime.h>
#include <hip/hip_bf16.h>

// Problem constants (from reference): M=100000 points, K=27 offsets, Cin=Cout=64.
#define NPTS 100000
#define KOFF 27
#define NCH  64

typedef __attribute__((ext_vector_type(8))) short bf16x8;   // 8 bf16 in 4 VGPRs
typedef __attribute__((ext_vector_type(8))) unsigned short u16x8;
typedef __attribute__((ext_vector_type(4))) float f32x4;

static __device__ __forceinline__ unsigned short f2bf(float x) {
  union { float f; unsigned int u; } v; v.f = x;
  unsigned int r = v.u + 0x7fffu + ((v.u >> 16) & 1u);   // RTNE
  return (unsigned short)(r >> 16);
}

// feats fp32 (M x 64) -> bf16 (M+1 x 64); row NPTS is all-zero (gather target for
// invalid rulebook entries). 8 elements / thread, 16B stores.
__global__ void convert_feats_kernel(const float* __restrict__ feats,
                                     unsigned short* __restrict__ fb) {
  size_t tid  = (size_t)blockIdx.x * blockDim.x + threadIdx.x;
  size_t base = tid * 8;
  const size_t valid_total = (size_t)NPTS * NCH;      // 6,400,000 (divisible by 8)
  const size_t total       = valid_total + NCH;       // + zero row
  if (base >= total) return;
  u16x8 r;
  if (base < valid_total) {
    const float4 a = *reinterpret_cast<const float4*>(feats + base);
    const float4 b = *reinterpret_cast<const float4*>(feats + base + 4);
    r[0] = f2bf(a.x); r[1] = f2bf(a.y); r[2] = f2bf(a.z); r[3] = f2bf(a.w);
    r[4] = f2bf(b.x); r[5] = f2bf(b.y); r[6] = f2bf(b.z); r[7] = f2bf(b.w);
  } else {
    #pragma unroll
    for (int j = 0; j < 8; ++j) r[j] = 0;
  }
  *reinterpret_cast<u16x8*>(fb + base) = r;
}

// weight fp32 [k][cin][cout] -> bf16 [k][cout][cin] (so a B-fragment's 8
// k-elements are 16 contiguous bytes).
__global__ void convert_weight_kernel(const float* __restrict__ w,
                                      unsigned short* __restrict__ wt) {
  int tid = blockIdx.x * 256 + threadIdx.x;
  if (tid >= KOFF * NCH * NCH) return;
  int ko  = tid >> 12;        // /4096
  int rem = tid & 4095;
  int o   = rem >> 6;
  int c   = rem & 63;
  wt[tid] = f2bf(w[(size_t)ko * 4096 + c * 64 + o]);
}

// Main kernel: block = 64 output rows x 64 cout. 4 waves; wave w owns rows
// [w*16, w*16+16). K-loop: 27 offsets x 2 chunks of cin=32.
// MFMA 16x16x32 bf16 layouts (HW-verified per guide):
//   A[i][k]: i = lane&15, k = 8*(lane>>4) + j   (j=0..7)
//   B[k][n]: n = lane&15, k = 8*(lane>>4) + j
//   D[i][n]: n = lane&15, i = 4*(lane>>4) + reg
__global__ __launch_bounds__(256)
void spconv_kernel(const unsigned short* __restrict__ fb,      // (NPTS+1) x 64 bf16
                   const int* __restrict__ rulebook,           // NPTS x 27 int32
                   const unsigned short* __restrict__ wt,      // 27 x 64 x 64 bf16 [k][o][c]
                   const float* __restrict__ feats,            // NPTS x 64 fp32 (residual)
                   const float* __restrict__ bias,             // 64 fp32
                   float* __restrict__ out) {                  // NPTS x 64 fp32
  __shared__ int s_idx[64][KOFF];
  __shared__ int s_cnt[64];

  const int tid = threadIdx.x;
  const int m0  = blockIdx.x * 64;

  if (tid < 64) s_cnt[tid] = 0;
  __syncthreads();

  // Stage rulebook indices (clamped: invalid -> zero row NPTS) + valid counts.
  for (int f = tid; f < 64 * KOFF; f += 256) {
    int r = f / KOFF, k = f - r * KOFF;
    int m = m0 + r;
    int idx = NPTS;
    if (m < NPTS) {
      int v = rulebook[(size_t)m * KOFF + k];
      if (v >= 0) { idx = v; atomicAdd(&s_cnt[r], 1); }
    }
    s_idx[r][k] = idx;
  }
  __syncthreads();

  const int wave = tid >> 6;
  const int lane = tid & 63;
  const int lr   = lane & 15;      // A-row / B-col / D-col within 16
  const int lk   = lane >> 4;      // k-subgroup
  const int coff = lk * 8;         // element offset within a 32-wide cin chunk
  const int row_local = wave * 16 + lr;

  f32x4 acc[4] = {f32x4{0,0,0,0}, f32x4{0,0,0,0}, f32x4{0,0,0,0}, f32x4{0,0,0,0}};

  for (int ko = 0; ko < KOFF; ++ko) {
    const int ridx = s_idx[row_local][ko];
    const unsigned short* frow = fb + (size_t)ridx * NCH;
    const bf16x8 a0 = *reinterpret_cast<const bf16x8*>(frow + coff);        // cin 0..31
    const bf16x8 a1 = *reinterpret_cast<const bf16x8*>(frow + 32 + coff);   // cin 32..63
    const unsigned short* wko = wt + ko * (NCH * NCH);
    #pragma unroll
    for (int nt = 0; nt < 4; ++nt) {
      const unsigned short* wrow = wko + (nt * 16 + lr) * NCH;
      const bf16x8 b0 = *reinterpret_cast<const bf16x8*>(wrow + coff);
      const bf16x8 b1 = *reinterpret_cast<const bf16x8*>(wrow + 32 + coff);
      acc[nt] = __builtin_amdgcn_mfma_f32_16x16x32_bf16(a0, b0, acc[nt], 0, 0, 0);
      acc[nt] = __builtin_amdgcn_mfma_f32_16x16x32_bf16(a1, b1, acc[nt], 0, 0, 0);
    }
  }

  // Epilogue: /denom + bias + residual, fp32.
  const int orow = wave * 16 + lk * 4;
  #pragma unroll
  for (int nt = 0; nt < 4; ++nt) {
    const int col = nt * 16 + lr;
    const float b = bias[col];
    #pragma unroll
    for (int i = 0; i < 4; ++i) {
      const int rl = orow + i;
      const int m  = m0 + rl;
      if (m < NPTS) {
        const float denom = (float)max(s_cnt[rl], 1);
        out[(size_t)m * NCH + col] =
            acc[nt][i] / denom + b + feats[(size_t)m * NCH + col];
      }
    }
  }
}

extern "C" void kernel_launch(void* const* d_in, const int* in_sizes, int n_in,
                              void* d_out, int out_size, void* d_ws, size_t ws_size,
                              hipStream_t stream) {
  const float* feats    = (const float*)d_in[0];
  const int*   rulebook = (const int*)d_in[1];
  const float* weight   = (const float*)d_in[2];
  const float* bias     = (const float*)d_in[3];
  float* out = (float*)d_out;

  // Workspace layout: [0, 12.8MB) feats bf16 (M+1 rows); then weight bf16.
  unsigned short* fb = (unsigned short*)d_ws;
  const size_t fb_bytes = (size_t)(NPTS + 1) * NCH * sizeof(unsigned short); // 12,800,128
  const size_t wt_off   = (fb_bytes + 255) & ~(size_t)255;                   // 16B-align+
  unsigned short* wt = (unsigned short*)((char*)d_ws + wt_off);

  {
    const size_t total = (size_t)(NPTS + 1) * NCH;        // bf16 elements
    const int threads = (int)((total + 7) / 8);
    convert_feats_kernel<<<(threads + 255) / 256, 256, 0, stream>>>(feats, fb);
  }
  {
    const int n = KOFF * NCH * NCH;
    convert_weight_kernel<<<(n + 255) / 256, 256, 0, stream>>>(weight, wt);
  }
  {
    const int nblk = (NPTS + 63) / 64;   // 1563
    spconv_kernel<<<nblk, 256, 0, stream>>>(fb, rulebook, wt, feats, bias, out);
  }
}